// Round 5
// baseline (1696.469 us; speedup 1.0000x reference)
//
#include <hip/hip_runtime.h>
#include <hip/hip_bf16.h>

#define N_ 1024
#define M_ 1152
#define L_ 32
#define NATSTRIDE (L_*M_)   // 36864
#define CONVK 129
#define OUTW 1024
#define NSTEP 31

typedef __attribute__((ext_vector_type(8))) short short8;
typedef __attribute__((ext_vector_type(4))) float f32x4;

__device__ __forceinline__ unsigned short f2bf(float f) {
    unsigned int u = __float_as_uint(f);
    u += 0x7FFFu + ((u >> 16) & 1u);   // round-to-nearest-even
    return (unsigned short)(u >> 16);
}
__device__ __forceinline__ float bf2f(unsigned short b) {
    return __uint_as_float(((unsigned int)b) << 16);
}

// Split convW[m][k][2] -> w0t[m][k], w1t[m][k] (bf16, k-contiguous = B^T layout)
__global__ __launch_bounds__(256) void build_wsplit(const float* __restrict__ convW,
                                                    unsigned short* __restrict__ w0t,
                                                    unsigned short* __restrict__ w1t) {
    int idx = blockIdx.x * blockDim.x + threadIdx.x;
    if (idx >= M_ * M_) return;
    int m = idx / M_;
    int k = idx - m * M_;
    const float* s = convW + (size_t)m * (2 * M_) + 2 * k;
    w0t[idx] = f2bf(s[0]);
    w1t[idx] = f2bf(s[1]);
}

// h0 = bf16(NATree[:, L-1, :])
__global__ __launch_bounds__(256) void build_h0(const float* __restrict__ nat,
                                                unsigned short* __restrict__ h0) {
    int idx = blockIdx.x * blockDim.x + threadIdx.x;
    if (idx >= N_ * M_) return;
    int n = idx / M_;
    int m = idx - n * M_;
    h0[idx] = f2bf(nat[(size_t)n * NATSTRIDE + (size_t)(L_ - 1) * M_ + m]);
}

// ---------------- Phase 1: Rpre = bf16( r_t @ W0^T + b ) for all t (unchanged R4) ----------------
#define P_BM 128
#define P_BN 128
#define P_BK 64
#define P_NT (M_ / P_BK)    // 18
#define P_LDP 72

__global__ __launch_bounds__(256) void rpre_gemm(
    const float* __restrict__ nat,
    const unsigned short* __restrict__ w0t,
    const float* __restrict__ convb,
    unsigned short* __restrict__ rpre)
{
    __shared__ __align__(16) unsigned short As[2][P_BM * P_LDP];
    __shared__ __align__(16) unsigned short Bs[2][P_BN * P_LDP];

    int tid = threadIdx.x;
    int lane = tid & 63;
    int w = tid >> 6;
    int wr = w >> 1, wc = w & 1;
    int raw = blockIdx.y * 9 + blockIdx.x;
    int logical = (raw & 7) * 279 + (raw >> 3);   // 2232 = 8*279 bijective chunked swizzle
    int bx = logical % 9, by = logical / 9;
    int n0 = by * P_BM;
    int m0 = bx * P_BN;
    int t = n0 >> 10;
    int l = (NSTEP - 1) - t;
    int nbase = n0 & 1023;
    const float* natR = nat + (size_t)l * M_;

    int lr = lane & 15;
    int lk = (lane >> 4) * 8;
    int srow = tid >> 3;
    int skcol = (tid & 7) * 8;

    f32x4 acc[4][4] = {};

    auto loadTile = [&](int it, short8 a[4], short8 b[4]) {
        int kb = it * P_BK;
        #pragma unroll
        for (int i = 0; i < 4; ++i) {
            int row = srow + i * 32;
            const float* s = natR + (size_t)(nbase + row) * NATSTRIDE + kb + skcol;
            f32x4 v0 = *(const f32x4*)(s);
            f32x4 v1 = *(const f32x4*)(s + 4);
            short8 tt;
            #pragma unroll
            for (int e = 0; e < 4; ++e) {
                tt[e]     = (short)f2bf(v0[e]);
                tt[4 + e] = (short)f2bf(v1[e]);
            }
            a[i] = tt;
            b[i] = *(const short8*)(w0t + (size_t)(m0 + row) * M_ + kb + skcol);
        }
    };
    auto writeTile = [&](int buf, short8 a[4], short8 b[4]) {
        #pragma unroll
        for (int i = 0; i < 4; ++i) {
            *(short8*)&As[buf][(srow + i * 32) * P_LDP + skcol] = a[i];
            *(short8*)&Bs[buf][(srow + i * 32) * P_LDP + skcol] = b[i];
        }
    };

    {
        short8 a0[4], b0[4];
        loadTile(0, a0, b0);
        writeTile(0, a0, b0);
    }
    __syncthreads();

    int cur = 0;
    for (int it = 0; it < P_NT; ++it) {
        short8 a2[4], b2[4];
        if (it + 1 < P_NT) loadTile(it + 1, a2, b2);

        #pragma unroll
        for (int ks = 0; ks < P_BK; ks += 32) {
            short8 af[4], bf_[4];
            #pragma unroll
            for (int mi = 0; mi < 4; ++mi)
                af[mi] = *(const short8*)&As[cur][(wr * 64 + mi * 16 + lr) * P_LDP + ks + lk];
            #pragma unroll
            for (int ni = 0; ni < 4; ++ni)
                bf_[ni] = *(const short8*)&Bs[cur][(wc * 64 + ni * 16 + lr) * P_LDP + ks + lk];
            #pragma unroll
            for (int mi = 0; mi < 4; ++mi)
                #pragma unroll
                for (int ni = 0; ni < 4; ++ni)
                    acc[mi][ni] = __builtin_amdgcn_mfma_f32_16x16x32_bf16(
                        af[mi], bf_[ni], acc[mi][ni], 0, 0, 0);
        }
        if (it + 1 < P_NT) {
            writeTile(cur ^ 1, a2, b2);
            __syncthreads();
            cur ^= 1;
        }
    }

    #pragma unroll
    for (int mi = 0; mi < 4; ++mi) {
        #pragma unroll
        for (int ni = 0; ni < 4; ++ni) {
            int mloc = m0 + wc * 64 + ni * 16 + lr;
            float bias = convb[mloc];
            #pragma unroll
            for (int j = 0; j < 4; ++j) {
                int g = n0 + wr * 64 + mi * 16 + (lane >> 4) * 4 + j;
                rpre[(size_t)g * M_ + mloc] = f2bf(acc[mi][ni][j] + bias);
            }
        }
    }
}

// ---------------- Phase 3: persistent chain kernel ----------------
// 144 blocks = 8 rowgrps (128 rows) x 18 colgrps (64 cols), 1 block/CU (160 KiB LDS).
// W1 col-panel resident in XOR-swizzled LDS; h streamed per step; per-ROWGRP barrier
// (block (rg,cg) only ever reads h rows of rg, written by blocks (rg,*)).
#define RG_ROWS 128
#define CG_COLS 64
#define C_BK 32
#define C_NT (M_ / C_BK)    // 36

__global__ __launch_bounds__(256) void chain_kernel(
    const float* __restrict__ nat,
    const unsigned short* __restrict__ w1t,
    const unsigned short* __restrict__ rpre,
    const float* __restrict__ x,
    unsigned short* __restrict__ h0buf,     // holds h_0 on entry; parity buffer 0
    unsigned short* __restrict__ h1buf,     // parity buffer 1
    float* __restrict__ res,
    unsigned int* __restrict__ bar)         // 8 counters, zeroed per launch
{
    // exactly 160 KiB
    __shared__ __align__(16) unsigned short Bs[CG_COLS * M_];      // 147456 B, swizzled
    __shared__ __align__(16) unsigned short As[2][RG_ROWS * C_BK]; // 16384 B, swizzled

    int tid = threadIdx.x;
    int lane = tid & 63;
    int w = tid >> 6;                 // wave: rows [32w, 32w+32)
    int lr = lane & 15;
    int lg = lane >> 4;               // 0..3
    int bid = blockIdx.x;
    int rg = bid & 7;                 // rowgrp (maps to XCD under round-robin dispatch)
    int cg = bid >> 3;                // colgrp 0..17
    int n0 = rg * RG_ROWS;
    int m0 = cg * CG_COLS;

    // ---- stage B panel once: w1t rows [m0, m0+64), all K, XOR-swizzled
    // elem (m,k) -> Bs[m*1152 + (k ^ ((m&7)<<3))]
    {
        int m = tid >> 2;             // 0..63
        int q = tid & 3;
        const unsigned short* src = w1t + (size_t)(m0 + m) * M_;
        #pragma unroll 4
        for (int j = 0; j < 36; ++j) {
            int c = q + j * 4;        // 16B chunk index 0..143
            short8 v = *(const short8*)(src + c * 8);
            *(short8*)&Bs[m * M_ + ((c * 8) ^ ((m & 7) << 3))] = v;
        }
    }

    // A staging helpers: elem (r,kl) -> As[buf][r*32 + (kl ^ ((r&3)<<3))]
    int ar = tid >> 1;                // 0..127
    int ah = tid & 1;                 // which 16-elem half
    auto gloadA = [&](const unsigned short* hin, int it, short8 v[2]) {
        const unsigned short* s = hin + (size_t)(n0 + ar) * M_ + it * C_BK + ah * 16;
        v[0] = *(const short8*)(s);
        v[1] = *(const short8*)(s + 8);
    };
    auto dswriteA = [&](int buf, short8 v[2]) {
        #pragma unroll
        for (int e = 0; e < 2; ++e) {
            int kl = ah * 16 + e * 8;
            *(short8*)&As[buf][ar * C_BK + (kl ^ ((ar & 3) << 3))] = v[e];
        }
    };

    f32x4 acc[2][4];

    for (int t = 0; t < NSTEP; ++t) {
        const unsigned short* hin = (t & 1) ? h1buf : h0buf;
        unsigned short* hout = (t & 1) ? h0buf : h1buf;
        const float* natR = nat + (size_t)((NSTEP - 1) - t) * M_;

        #pragma unroll
        for (int mi = 0; mi < 2; ++mi)
            #pragma unroll
            for (int ni = 0; ni < 4; ++ni)
                acc[mi][ni] = (f32x4){0.f, 0.f, 0.f, 0.f};

        short8 rcur[2], rnxt[2], rfut[2];
        gloadA(hin, 0, rcur);
        dswriteA(0, rcur);
        gloadA(hin, 1, rnxt);
        __syncthreads();              // As[0] ready (covers B-stage on t==0)

        int cur = 0;
        for (int it = 0; it < C_NT; ++it) {
            if (it + 2 < C_NT) gloadA(hin, it + 2, rfut);
            if (it + 1 < C_NT) dswriteA(cur ^ 1, rnxt);

            short8 af[2], bf_[4];
            #pragma unroll
            for (int mi = 0; mi < 2; ++mi) {
                int r = 32 * w + 16 * mi + lr;
                af[mi] = *(const short8*)&As[cur][r * C_BK + ((lg * 8) ^ ((r & 3) << 3))];
            }
            #pragma unroll
            for (int ni = 0; ni < 4; ++ni) {
                int m = 16 * ni + lr;
                int c = it * 4 + lg;
                bf_[ni] = *(const short8*)&Bs[m * M_ + ((c * 8) ^ ((m & 7) << 3))];
            }
            #pragma unroll
            for (int mi = 0; mi < 2; ++mi)
                #pragma unroll
                for (int ni = 0; ni < 4; ++ni)
                    acc[mi][ni] = __builtin_amdgcn_mfma_f32_16x16x32_bf16(
                        af[mi], bf_[ni], acc[mi][ni], 0, 0, 0);

            __syncthreads();          // As[cur] consumed; As[cur^1] written
            cur ^= 1;
            rnxt[0] = rfut[0]; rnxt[1] = rfut[1];
        }

        // epilogue
        int final_step = (t == NSTEP - 1);
        #pragma unroll
        for (int mi = 0; mi < 2; ++mi) {
            #pragma unroll
            for (int ni = 0; ni < 4; ++ni) {
                int mloc = m0 + ni * 16 + lr;
                #pragma unroll
                for (int j = 0; j < 4; ++j) {
                    int nloc = n0 + 32 * w + 16 * mi + (lane >> 4) * 4 + j;
                    float pre = acc[mi][ni][j] + bf2f(rpre[(size_t)t * N_ * M_ + (size_t)nloc * M_ + mloc]);
                    float hv = tanhf(pre) + natR[(size_t)nloc * NATSTRIDE + mloc];
                    if (final_step) {
                        res[(size_t)nloc * M_ + mloc] = tanhf(tanhf(hv) + x[(size_t)nloc * M_ + mloc]);
                    } else {
                        hout[(size_t)nloc * M_ + mloc] = f2bf(hv);
                    }
                }
            }
        }

        // per-rowgrp barrier (18 blocks), device-scope; skip after final step
        if (!final_step) {
            __threadfence();
            __syncthreads();
            if (tid == 0) {
                atomicAdd(&bar[rg], 1u);
                unsigned int target = 18u * (unsigned)(t + 1);
                while (__hip_atomic_load(&bar[rg], __ATOMIC_ACQUIRE,
                                         __HIP_MEMORY_SCOPE_AGENT) < target) {
                    __builtin_amdgcn_s_sleep(2);
                }
            }
            __syncthreads();
            __threadfence();
        }
    }
}

// out[n][j] = conv2b + sum_k res[n][j+k] * conv2W[k]
__global__ __launch_bounds__(256) void conv_out_kernel(
    const float* __restrict__ res, const float* __restrict__ w2,
    const float* __restrict__ b2, float* __restrict__ out)
{
    __shared__ float row[M_];
    __shared__ float wk[CONVK];
    int n = blockIdx.x;
    int tid = threadIdx.x;
    for (int i = tid; i < M_; i += 256) row[i] = res[(size_t)n * M_ + i];
    if (tid < CONVK) wk[tid] = w2[tid];
    __syncthreads();
    float b = b2[0];
    int j0 = tid * 4;
    float s0 = b, s1 = b, s2 = b, s3 = b;
    float r0 = row[j0], r1 = row[j0 + 1], r2 = row[j0 + 2], r3 = row[j0 + 3];
    for (int k = 0; k < CONVK; ++k) {
        float wv = wk[k];
        s0 += r0 * wv; s1 += r1 * wv; s2 += r2 * wv; s3 += r3 * wv;
        if (k < CONVK - 1) { r0 = r1; r1 = r2; r2 = r3; r3 = row[j0 + 4 + k]; }
    }
    float* o = out + (size_t)n * OUTW + j0;
    o[0] = s0; o[1] = s1; o[2] = s2; o[3] = s3;
}

extern "C" void kernel_launch(void* const* d_in, const int* in_sizes, int n_in,
                              void* d_out, int out_size, void* d_ws, size_t ws_size,
                              hipStream_t stream) {
    const float* NATree = (const float*)d_in[0];
    const float* x      = (const float*)d_in[1];
    const float* convW  = (const float*)d_in[2];
    const float* convb  = (const float*)d_in[3];
    const float* conv2W = (const float*)d_in[4];
    const float* conv2b = (const float*)d_in[5];
    float* out = (float*)d_out;

    char* ws = (char*)d_ws;
    size_t off = 0;
    auto alloc = [&](size_t bytes) {
        void* p = ws + off;
        off = (off + bytes + 255) & ~(size_t)255;
        return p;
    };
    unsigned short* w0t  = (unsigned short*)alloc((size_t)M_ * M_ * 2);
    unsigned short* w1t  = (unsigned short*)alloc((size_t)M_ * M_ * 2);
    unsigned short* hA   = (unsigned short*)alloc((size_t)N_ * M_ * 2);
    unsigned short* hB   = (unsigned short*)alloc((size_t)N_ * M_ * 2);
    unsigned short* rpre = (unsigned short*)alloc((size_t)NSTEP * N_ * M_ * 2);
    float*          res  = (float*)alloc((size_t)N_ * M_ * 4);
    unsigned int*   bar  = (unsigned int*)alloc(256);

    hipMemsetAsync(bar, 0, 256, stream);
    build_wsplit<<<(M_ * M_ + 255) / 256, 256, 0, stream>>>(convW, w0t, w1t);
    build_h0<<<(N_ * M_ + 255) / 256, 256, 0, stream>>>(NATree, hA);

    // Phase 1: all 31 r_t @ W0^T + b in one GEMM (M = 31744)
    rpre_gemm<<<dim3(M_ / P_BN, (NSTEP * N_) / P_BM), 256, 0, stream>>>(NATree, w0t, convb, rpre);

    // Phase 3: persistent chain (144 blocks = 1/CU; per-rowgrp barriers inside)
    chain_kernel<<<144, 256, 0, stream>>>(NATree, w1t, rpre, x, hA, hB, res, bar);

    conv_out_kernel<<<1024, 256, 0, stream>>>(res, conv2W, conv2b, out);
}

// Round 6
// 790.715 us; speedup vs baseline: 2.1455x; 2.1455x over previous
//
#include <hip/hip_runtime.h>
#include <hip/hip_bf16.h>

#define N_ 1024
#define M_ 1152
#define L_ 32
#define NATSTRIDE (L_*M_)   // 36864
#define CONVK 129
#define OUTW 1024
#define NSTEP 31

typedef __attribute__((ext_vector_type(8))) short short8;
typedef __attribute__((ext_vector_type(4))) float f32x4;

__device__ __forceinline__ unsigned short f2bf(float f) {
    unsigned int u = __float_as_uint(f);
    u += 0x7FFFu + ((u >> 16) & 1u);   // round-to-nearest-even
    return (unsigned short)(u >> 16);
}
__device__ __forceinline__ float bf2f(unsigned short b) {
    return __uint_as_float(((unsigned int)b) << 16);
}

// Split convW[m][k][2] -> w0t[m][k], w1t[m][k] (bf16, k-contiguous = B^T layout)
__global__ __launch_bounds__(256) void build_wsplit(const float* __restrict__ convW,
                                                    unsigned short* __restrict__ w0t,
                                                    unsigned short* __restrict__ w1t) {
    int idx = blockIdx.x * blockDim.x + threadIdx.x;
    if (idx >= M_ * M_) return;
    int m = idx / M_;
    int k = idx - m * M_;
    const float* s = convW + (size_t)m * (2 * M_) + 2 * k;
    w0t[idx] = f2bf(s[0]);
    w1t[idx] = f2bf(s[1]);
}

// h0 = bf16(NATree[:, L-1, :])
__global__ __launch_bounds__(256) void build_h0(const float* __restrict__ nat,
                                                unsigned short* __restrict__ h0) {
    int idx = blockIdx.x * blockDim.x + threadIdx.x;
    if (idx >= N_ * M_) return;
    int n = idx / M_;
    int m = idx - n * M_;
    h0[idx] = f2bf(nat[(size_t)n * NATSTRIDE + (size_t)(L_ - 1) * M_ + m]);
}

// rbf[t][n][m] = bf16(NATree[n][30-t][m])  for t = 0..30  (r_t levels, coalesced bf16)
__global__ __launch_bounds__(256) void build_rbf(const float* __restrict__ nat,
                                                 unsigned short* __restrict__ rbf) {
    int idx = blockIdx.x * blockDim.x + threadIdx.x;   // one thread per 8 elems
    if (idx >= NSTEP * N_ * M_ / 8) return;
    int o = idx * 8;
    int t = o / (N_ * M_);
    int rem = o - t * (N_ * M_);
    int n = rem / M_;
    int m = rem - n * M_;
    int l = (NSTEP - 1) - t;
    const float* s = nat + (size_t)n * NATSTRIDE + (size_t)l * M_ + m;
    f32x4 v0 = *(const f32x4*)(s);
    f32x4 v1 = *(const f32x4*)(s + 4);
    short8 tt;
    #pragma unroll
    for (int e = 0; e < 4; ++e) {
        tt[e]     = (short)f2bf(v0[e]);
        tt[4 + e] = (short)f2bf(v1[e]);
    }
    *(short8*)(rbf + o) = tt;
}

// ---------------- Phase 1: Rpre = bf16( r_t @ W0^T + b ) for all t ----------------
// A = rbf (bf16, rows t*1024+n contiguous). 128x128 tile, BK=64 dbuf, chunked XCD swizzle.
#define P_BM 128
#define P_BN 128
#define P_BK 64
#define P_NT (M_ / P_BK)    // 18
#define P_LDP 72

__global__ __launch_bounds__(256) void rpre_gemm(
    const unsigned short* __restrict__ rbf,
    const unsigned short* __restrict__ w0t,
    const float* __restrict__ convb,
    unsigned short* __restrict__ rpre)
{
    __shared__ __align__(16) unsigned short As[2][P_BM * P_LDP];
    __shared__ __align__(16) unsigned short Bs[2][P_BN * P_LDP];

    int tid = threadIdx.x;
    int lane = tid & 63;
    int w = tid >> 6;
    int wr = w >> 1, wc = w & 1;
    int raw = blockIdx.y * 9 + blockIdx.x;
    int logical = (raw & 7) * 279 + (raw >> 3);   // 2232 = 8*279 bijective chunked swizzle
    int bx = logical % 9, by = logical / 9;
    int n0 = by * P_BM;                           // row in [0, 31744)
    int m0 = bx * P_BN;

    int lr = lane & 15;
    int lk = (lane >> 4) * 8;
    int srow = tid >> 3;
    int skcol = (tid & 7) * 8;

    f32x4 acc[4][4] = {};

    auto loadTile = [&](int it, short8 a[4], short8 b[4]) {
        int kb = it * P_BK;
        #pragma unroll
        for (int i = 0; i < 4; ++i) {
            int row = srow + i * 32;
            a[i] = *(const short8*)(rbf + (size_t)(n0 + row) * M_ + kb + skcol);
            b[i] = *(const short8*)(w0t + (size_t)(m0 + row) * M_ + kb + skcol);
        }
    };
    auto writeTile = [&](int buf, short8 a[4], short8 b[4]) {
        #pragma unroll
        for (int i = 0; i < 4; ++i) {
            *(short8*)&As[buf][(srow + i * 32) * P_LDP + skcol] = a[i];
            *(short8*)&Bs[buf][(srow + i * 32) * P_LDP + skcol] = b[i];
        }
    };

    {
        short8 a0[4], b0[4];
        loadTile(0, a0, b0);
        writeTile(0, a0, b0);
    }
    __syncthreads();

    int cur = 0;
    for (int it = 0; it < P_NT; ++it) {
        short8 a2[4], b2[4];
        if (it + 1 < P_NT) loadTile(it + 1, a2, b2);

        #pragma unroll
        for (int ks = 0; ks < P_BK; ks += 32) {
            short8 af[4], bf_[4];
            #pragma unroll
            for (int mi = 0; mi < 4; ++mi)
                af[mi] = *(const short8*)&As[cur][(wr * 64 + mi * 16 + lr) * P_LDP + ks + lk];
            #pragma unroll
            for (int ni = 0; ni < 4; ++ni)
                bf_[ni] = *(const short8*)&Bs[cur][(wc * 64 + ni * 16 + lr) * P_LDP + ks + lk];
            #pragma unroll
            for (int mi = 0; mi < 4; ++mi)
                #pragma unroll
                for (int ni = 0; ni < 4; ++ni)
                    acc[mi][ni] = __builtin_amdgcn_mfma_f32_16x16x32_bf16(
                        af[mi], bf_[ni], acc[mi][ni], 0, 0, 0);
        }
        if (it + 1 < P_NT) {
            writeTile(cur ^ 1, a2, b2);
            __syncthreads();
            cur ^= 1;
        }
    }

    #pragma unroll
    for (int mi = 0; mi < 4; ++mi) {
        #pragma unroll
        for (int ni = 0; ni < 4; ++ni) {
            int mloc = m0 + wc * 64 + ni * 16 + lr;
            float bias = convb[mloc];
            #pragma unroll
            for (int j = 0; j < 4; ++j) {
                int g = n0 + wr * 64 + mi * 16 + (lane >> 4) * 4 + j;
                rpre[(size_t)g * M_ + mloc] = f2bf(acc[mi][ni][j] + bias);
            }
        }
    }
}

// ---------------- Phase 3 (x31): C = h@W1^T; hv = tanh(C + Rpre_t) + r_t ----------------
// 64x64 tile, 4 waves (2x2 of 32x32), BK=128 (9 K-iters), dbuf.
#define S_BM 64
#define S_BN 64
#define S_BK 128
#define S_NT (M_ / S_BK)    // 9
#define S_LDP 136

__global__ __launch_bounds__(256) void step_kernel(
    const unsigned short* __restrict__ hIn,
    const unsigned short* __restrict__ w1t,
    const unsigned short* __restrict__ rpre_t,
    const unsigned short* __restrict__ rbf_t,   // bf16 r_t rows, stride M_
    const float* __restrict__ x,
    unsigned short* __restrict__ hOut,
    float* __restrict__ resOut,
    int final_step)
{
    __shared__ __align__(16) unsigned short As[2][S_BM * S_LDP];
    __shared__ __align__(16) unsigned short Bs[2][S_BN * S_LDP];

    int tid = threadIdx.x;
    int lane = tid & 63;
    int w = tid >> 6;
    int wr = w >> 1, wc = w & 1;
    int bid = blockIdx.y * 18 + blockIdx.x;
    int swz = (bid & 7) * 36 + (bid >> 3);   // 288 % 8 == 0 -> bijective XCD swizzle
    int bx = swz % 18, by = swz / 18;
    int n0 = by * S_BM;
    int m0 = bx * S_BN;
    int lr = lane & 15;
    int lk = (lane >> 4) * 8;
    int srow = tid >> 4;                     // 16 rows per pass, 4 passes
    int skcol = (tid & 15) * 8;

    f32x4 acc[2][2] = {};

    auto loadTile = [&](int it, short8 a[4], short8 b[4]) {
        int kb = it * S_BK;
        #pragma unroll
        for (int i = 0; i < 4; ++i) {
            int row = srow + i * 16;
            a[i] = *(const short8*)(hIn + (size_t)(n0 + row) * M_ + kb + skcol);
            b[i] = *(const short8*)(w1t + (size_t)(m0 + row) * M_ + kb + skcol);
        }
    };
    auto writeTile = [&](int buf, short8 a[4], short8 b[4]) {
        #pragma unroll
        for (int i = 0; i < 4; ++i) {
            *(short8*)&As[buf][(srow + i * 16) * S_LDP + skcol] = a[i];
            *(short8*)&Bs[buf][(srow + i * 16) * S_LDP + skcol] = b[i];
        }
    };

    {
        short8 a0[4], b0[4];
        loadTile(0, a0, b0);
        writeTile(0, a0, b0);
    }
    __syncthreads();

    int cur = 0;
    for (int it = 0; it < S_NT; ++it) {
        short8 a2[4], b2[4];
        if (it + 1 < S_NT) loadTile(it + 1, a2, b2);

        #pragma unroll
        for (int ks = 0; ks < S_BK; ks += 32) {
            short8 af[2], bf_[2];
            #pragma unroll
            for (int mi = 0; mi < 2; ++mi)
                af[mi] = *(const short8*)&As[cur][(wr * 32 + mi * 16 + lr) * S_LDP + ks + lk];
            #pragma unroll
            for (int ni = 0; ni < 2; ++ni)
                bf_[ni] = *(const short8*)&Bs[cur][(wc * 32 + ni * 16 + lr) * S_LDP + ks + lk];
            #pragma unroll
            for (int mi = 0; mi < 2; ++mi)
                #pragma unroll
                for (int ni = 0; ni < 2; ++ni)
                    acc[mi][ni] = __builtin_amdgcn_mfma_f32_16x16x32_bf16(
                        af[mi], bf_[ni], acc[mi][ni], 0, 0, 0);
        }
        if (it + 1 < S_NT) {
            writeTile(cur ^ 1, a2, b2);
            __syncthreads();
            cur ^= 1;
        }
    }

    #pragma unroll
    for (int mi = 0; mi < 2; ++mi) {
        #pragma unroll
        for (int ni = 0; ni < 2; ++ni) {
            int mloc = m0 + wc * 32 + ni * 16 + lr;
            #pragma unroll
            for (int j = 0; j < 4; ++j) {
                int nloc = n0 + wr * 32 + mi * 16 + (lane >> 4) * 4 + j;
                float pre = acc[mi][ni][j] + bf2f(rpre_t[(size_t)nloc * M_ + mloc]);
                float hv = tanhf(pre) + bf2f(rbf_t[(size_t)nloc * M_ + mloc]);
                if (final_step) {
                    float res = tanhf(tanhf(hv) + x[(size_t)nloc * M_ + mloc]);
                    resOut[(size_t)nloc * M_ + mloc] = res;
                } else {
                    hOut[(size_t)nloc * M_ + mloc] = f2bf(hv);
                }
            }
        }
    }
}

// out[n][j] = conv2b + sum_k res[n][j+k] * conv2W[k]
__global__ __launch_bounds__(256) void conv_out_kernel(
    const float* __restrict__ res, const float* __restrict__ w2,
    const float* __restrict__ b2, float* __restrict__ out)
{
    __shared__ float row[M_];
    __shared__ float wk[CONVK];
    int n = blockIdx.x;
    int tid = threadIdx.x;
    for (int i = tid; i < M_; i += 256) row[i] = res[(size_t)n * M_ + i];
    if (tid < CONVK) wk[tid] = w2[tid];
    __syncthreads();
    float b = b2[0];
    int j0 = tid * 4;
    float s0 = b, s1 = b, s2 = b, s3 = b;
    float r0 = row[j0], r1 = row[j0 + 1], r2 = row[j0 + 2], r3 = row[j0 + 3];
    for (int k = 0; k < CONVK; ++k) {
        float wv = wk[k];
        s0 += r0 * wv; s1 += r1 * wv; s2 += r2 * wv; s3 += r3 * wv;
        if (k < CONVK - 1) { r0 = r1; r1 = r2; r2 = r3; r3 = row[j0 + 4 + k]; }
    }
    float* o = out + (size_t)n * OUTW + j0;
    o[0] = s0; o[1] = s1; o[2] = s2; o[3] = s3;
}

extern "C" void kernel_launch(void* const* d_in, const int* in_sizes, int n_in,
                              void* d_out, int out_size, void* d_ws, size_t ws_size,
                              hipStream_t stream) {
    const float* NATree = (const float*)d_in[0];
    const float* x      = (const float*)d_in[1];
    const float* convW  = (const float*)d_in[2];
    const float* convb  = (const float*)d_in[3];
    const float* conv2W = (const float*)d_in[4];
    const float* conv2b = (const float*)d_in[5];
    float* out = (float*)d_out;

    char* ws = (char*)d_ws;
    size_t off = 0;
    auto alloc = [&](size_t bytes) {
        void* p = ws + off;
        off = (off + bytes + 255) & ~(size_t)255;
        return p;
    };
    unsigned short* w0t  = (unsigned short*)alloc((size_t)M_ * M_ * 2);
    unsigned short* w1t  = (unsigned short*)alloc((size_t)M_ * M_ * 2);
    unsigned short* hA   = (unsigned short*)alloc((size_t)N_ * M_ * 2);
    unsigned short* hB   = (unsigned short*)alloc((size_t)N_ * M_ * 2);
    unsigned short* rpre = (unsigned short*)alloc((size_t)NSTEP * N_ * M_ * 2);
    unsigned short* rbf  = (unsigned short*)alloc((size_t)NSTEP * N_ * M_ * 2);
    float*          res  = (float*)alloc((size_t)N_ * M_ * 4);

    build_wsplit<<<(M_ * M_ + 255) / 256, 256, 0, stream>>>(convW, w0t, w1t);
    build_h0<<<(N_ * M_ + 255) / 256, 256, 0, stream>>>(NATree, hA);
    build_rbf<<<(NSTEP * N_ * M_ / 8 + 255) / 256, 256, 0, stream>>>(NATree, rbf);

    // Phase 1: all 31 r_t @ W0^T + b in one GEMM (M = 31744), 128x128 tiles
    rpre_gemm<<<dim3(M_ / P_BN, (NSTEP * N_) / P_BM), 256, 0, stream>>>(rbf, w0t, convb, rpre);

    // Phase 3: sequential h-chain
    const unsigned short* hin = hA;
    unsigned short* hout = hB;
    for (int t = 0; t < NSTEP; ++t) {
        int fin = (t == NSTEP - 1) ? 1 : 0;
        step_kernel<<<dim3(M_ / S_BN, N_ / S_BM), 256, 0, stream>>>(
            hin, w1t, rpre + (size_t)t * N_ * M_, rbf + (size_t)t * N_ * M_,
            x, hout, res, fin);
        unsigned short* tmp = hout;
        hout = (unsigned short*)hin;
        hin = tmp;
    }

    conv_out_kernel<<<1024, 256, 0, stream>>>(res, conv2W, conv2b, out);
}